// Round 1
// 551.835 us; speedup vs baseline: 1.2606x; 1.2606x over previous
//
#include <hip/hip_runtime.h>
#include <cmath>

#define N_PTS 200000
#define HD 64
#define CD 128
#define KEEP 63

typedef __bf16 bf16;
typedef __bf16 bf16x4 __attribute__((ext_vector_type(4)));
typedef __bf16 bf16x8 __attribute__((ext_vector_type(8)));
typedef float f32x4 __attribute__((ext_vector_type(4)));
typedef float f32x16 __attribute__((ext_vector_type(16)));

__device__ __forceinline__ float elu_f(float v) {
    return v > 0.f ? v : __expf(v) - 1.f;
}

// ---------------------------------------------------------------------------
// K0: prep weights + zero-page.
//   WbT layout is now FRAGMENT-MAJOR so each A-frag load in k_conv is a fully
//   coalesced 1 KB wave read (8 lines) instead of 32 scattered 32B segments:
//     WbT[k][frag = (i>>4)*2 + (o>>5)][lane = ((i>>3)&1)*32 + (o&31)][e = i&7]
//   WaT gets the same treatment for k_stage1 (16 frags of 512 elems).
//   WcT unchanged. zp re-zeroed every call (ws is poisoned 0xAA).
// ---------------------------------------------------------------------------
__global__ __launch_bounds__(256) void k_prep(const float* __restrict__ Wb,
                                              const float* __restrict__ Wc,
                                              const float* __restrict__ Wa,
                                              bf16* __restrict__ WbT,
                                              bf16* __restrict__ WcT,
                                              bf16* __restrict__ WaT,
                                              bf16* __restrict__ zp) {
    int idx = blockIdx.x * 256 + threadIdx.x;
    if (idx < KEEP * HD * HD) {
        int k = idx >> 12;
        int rem = idx & 4095;
        int o = rem >> 6, i = rem & 63;     // o = out-row, i = in-col
        int dst = ((i >> 4) * 2 + (o >> 5)) * 512 +
                  (((i >> 3) & 1) * 32 + (o & 31)) * 8 + (i & 7);
        WbT[(k << 12) + dst] = (bf16)Wb[(k * HD + i) * HD + o];
        return;
    }
    int e = idx - KEEP * HD * HD;
    if (e < CD * HD) {           // WcT (layout unchanged)
        int c = e >> 6, h = e & 63;
        WcT[e] = (bf16)Wc[h * CD + c];
        return;
    }
    e -= CD * HD;
    if (e < HD * CD) {           // WaT, fragment-major
        int o = e >> 7, c = e & 127;
        int dst = ((c >> 4) * 2 + (o >> 5)) * 512 +
                  (((c >> 3) & 1) * 32 + (o & 31)) * 8 + (c & 7);
        WaT[dst] = (bf16)Wa[c * HD + o];
        return;
    }
    e -= HD * CD;
    if (e < 64) zp[e] = (bf16)0.f;
}

// ---------------------------------------------------------------------------
// K1: f[n][h] = elu( elu(x[n]+y[n]) @ Wa ), bf16.  MFMA version.
//   Pipelined so every vmcnt wait is COUNTED (no per-iter drain):
//     per ks: [A-frags (coalesced)] [x/y chunks for ks+1] [bv VALU + MFMA]
//   bv(ks) consumes loads issued LAST iteration -> vmcnt(10);
//   MFMA consumes A issued BEFORE the ks+1 loads -> vmcnt(8).
// ---------------------------------------------------------------------------
__global__ __launch_bounds__(256, 4) void k_stage1(const float* __restrict__ x,
                                                   const float* __restrict__ y,
                                                   const bf16* __restrict__ WaT,
                                                   bf16* __restrict__ f) {
    __shared__ bf16 pbuf[4][32 * 64];   // 16 KB, per-wave transpose buffer
    int tid = threadIdx.x;
    int wave = tid >> 6;
    int lane = tid & 63;
    int l31 = lane & 31;
    int half = lane >> 5;
    int pbase_w = blockIdx.x * 128 + wave * 32;
    int p = pbase_w + l31;
    int pc = p < N_PTS ? p : N_PTS - 1;     // clamp loads; stores guarded

    const float* xr = x + (size_t)pc * CD;
    const float* yr = y + (size_t)pc * CD;

    f32x16 acc[2];
#pragma unroll
    for (int mt = 0; mt < 2; mt++)
#pragma unroll
        for (int r = 0; r < 16; r++) acc[mt][r] = 0.f;

    f32x4 xa[2], xb[2], ya[2], yb[2];
    {
        int c0 = half * 8;
        xa[0] = *(const f32x4*)(xr + c0);
        xb[0] = *(const f32x4*)(xr + c0 + 4);
        ya[0] = *(const f32x4*)(yr + c0);
        yb[0] = *(const f32x4*)(yr + c0 + 4);
    }
#pragma unroll
    for (int ks = 0; ks < 8; ks++) {
        int cur = ks & 1, nxt = cur ^ 1;
        // A-frags first: issued BEFORE the prefetch loads so their wait is
        // vmcnt(8), leaving next-iter x/y in flight.
        bf16x8 a0 = *(const bf16x8*)(WaT + (ks * 2 + 0) * 512 + lane * 8);
        bf16x8 a1 = *(const bf16x8*)(WaT + (ks * 2 + 1) * 512 + lane * 8);
        __builtin_amdgcn_sched_barrier(0);
        if (ks < 7) {
            int c0 = half * 8 + (ks + 1) * 16;
            xa[nxt] = *(const f32x4*)(xr + c0);
            xb[nxt] = *(const f32x4*)(xr + c0 + 4);
            ya[nxt] = *(const f32x4*)(yr + c0);
            yb[nxt] = *(const f32x4*)(yr + c0 + 4);
        }
        bf16x8 bv;
#pragma unroll
        for (int jj = 0; jj < 4; jj++) {
            bv[jj]     = (bf16)elu_f(xa[cur][jj] + ya[cur][jj]);
            bv[4 + jj] = (bf16)elu_f(xb[cur][jj] + yb[cur][jj]);
        }
        acc[0] = __builtin_amdgcn_mfma_f32_32x32x16_bf16(a0, bv, acc[0], 0, 0, 0);
        acc[1] = __builtin_amdgcn_mfma_f32_32x32x16_bf16(a1, bv, acc[1], 0, 0, 0);
        __builtin_amdgcn_sched_barrier(0);
    }

    // elu + scatter into pbuf [point][h] (XOR-swizzled 16B chunks), then
    // coalesced 16B stores.  Per-wave buffer: no barrier needed.
    bf16* pb = pbuf[wave];
#pragma unroll
    for (int mt = 0; mt < 2; mt++) {
#pragma unroll
        for (int q = 0; q < 4; q++) {
            bf16x4 v;
#pragma unroll
            for (int jj = 0; jj < 4; jj++)
                v[jj] = (bf16)elu_f(acc[mt][q * 4 + jj]);
            int chunk = mt * 4 + q;   // h = chunk*8 + 4*half + j
            *(bf16x4*)&pb[l31 * 64 + ((chunk ^ (l31 & 7)) * 8) + 4 * half] = v;
        }
    }
#pragma unroll
    for (int qq = 0; qq < 4; qq++) {
        int t = lane + 64 * qq;          // 0..255 chunk ids
        int row = t >> 3, ch = t & 7;
        int pos = ch ^ (row & 7);
        bf16x8 v = *(const bf16x8*)&pb[row * 64 + pos * 8];
        int pp = pbase_w + row;
        if (pp < N_PTS)
            *(bf16x8*)(f + (size_t)pp * HD + ch * 8) = v;
    }
}

// ---------------------------------------------------------------------------
// K2: conv + fused epilogue.  64 pts/wave, 4 waves/wg.
//   Per-substep issue order (pinned by sched_barrier so the machine scheduler
//   cannot reorder the vmcnt queue):
//       [A-frags(k) coalesced] [gather(k+2)] [nidx(k+5)] [16x MFMA(k)]
//   A is issued BEFORE the prefetches -> the MFMA wait is vmcnt(10), NOT a
//   drain: gathers keep >=1 substep of slack, nidx completes by the NEXT
//   substep's counted wait (~1.5-2k cyc with 3-4 waves/SIMD > HBM latency).
//   Previous version issued A last -> vmcnt(0) drain of all prefetches every
//   substep = the 90%-idle latency wall the counters showed.
// ---------------------------------------------------------------------------
struct BB { bf16x8 v[4]; };
struct AF { bf16x8 v[8]; };

__global__ __launch_bounds__(256, 2) void k_conv(const bf16* __restrict__ f,
                                                 const int* __restrict__ nidx,
                                                 const bf16* __restrict__ WbT,
                                                 const bf16* __restrict__ WcT,
                                                 const bf16* __restrict__ zp,
                                                 const float* __restrict__ x,
                                                 float* __restrict__ out) {
    __shared__ bf16 wcs[128 * 64];       // 16 KB : WcT, XOR-swizzled
    __shared__ bf16 pbuf[4 * 32 * 64];   // 16 KB : per-wave transpose buf

    int tid = threadIdx.x;
    int wave = tid >> 6;
    int lane = tid & 63;
    int l31 = lane & 31;
    int half = lane >> 5;
    int pbase = blockIdx.x * 256 + wave * 64;
    int p0 = pbase + l31;
    int p1 = pbase + 32 + l31;

    f32x16 acc[2][2];
#pragma unroll
    for (int a = 0; a < 2; a++)
#pragma unroll
        for (int b = 0; b < 2; b++)
#pragma unroll
            for (int r = 0; r < 16; r++) acc[a][b][r] = 0.f;

    // stage WcT (consumed after the one barrier before the epilogue)
#pragma unroll
    for (int L = tid; L < 1024; L += 256) {
        int c = L >> 3, ci = L & 7;
        bf16x8 v = *(const bf16x8*)&WcT[L * 8];
        *(bf16x8*)&wcs[c * 64 + ((ci ^ (c & 7)) * 8)] = v;
    }

    auto ldidx = [&](int k, int pp) -> int {
        return (k < KEEP && pp < N_PTS) ? nidx[(size_t)k * N_PTS + pp] : -1;
    };
    auto baddr = [&](int iv) -> const bf16* {
        return iv >= 0 ? f + (size_t)iv * HD + half * 8 : zp + half * 8;
    };
    auto gather = [&](BB& b, const bf16* a) {
#pragma unroll
        for (int ks = 0; ks < 4; ks++)
            b.v[ks] = *(const bf16x8*)(a + ks * 16);
    };
    auto loadA = [&](int k, AF& A) {
        const bf16* wk = WbT + ((size_t)k << 12);
#pragma unroll
        for (int fi = 0; fi < 8; fi++)     // 8 fully-coalesced 1KB wave reads
            A.v[fi] = *(const bf16x8*)(wk + fi * 512 + lane * 8);
    };
    auto mstep = [&](const AF& A, BB& q0, BB& q1) {
#pragma unroll
        for (int ks = 0; ks < 4; ks++) {
#pragma unroll
            for (int mt = 0; mt < 2; mt++) {
                acc[mt][0] = __builtin_amdgcn_mfma_f32_32x32x16_bf16(A.v[ks * 2 + mt], q0.v[ks], acc[mt][0], 0, 0, 0);
                acc[mt][1] = __builtin_amdgcn_mfma_f32_32x32x16_bf16(A.v[ks * 2 + mt], q1.v[ks], acc[mt][1], 0, 0, 0);
            }
        }
    };

    // prologue: B slots b0=k0, b1=k1; idx slots: s2=k2, s0=k3, s1=k4
    BB b0a, b0b, b1a, b1b, b2a, b2b;
    int i2a = ldidx(2, p0), i2b = ldidx(2, p1);
    int i0a = ldidx(3, p0), i0b = ldidx(3, p1);
    int i1a = ldidx(4, p0), i1b = ldidx(4, p1);
    {
        int ja = ldidx(0, p0), jb = ldidx(0, p1);
        int ka = ldidx(1, p0), kb = ldidx(1, p1);
        gather(b0a, baddr(ja)); gather(b0b, baddr(jb));
        gather(b1a, baddr(ka)); gather(b1b, baddr(kb));
    }

    // invariant entering body j (k=3j): b0=k, b1=k+1, idx slots k+2,k+3,k+4
    AF Af;
    for (int j = 0; j < 20; j++) {
        int k = 3 * j;
        loadA(k, Af);
        __builtin_amdgcn_sched_barrier(0);
        gather(b2a, baddr(i2a)); gather(b2b, baddr(i2b));   // k+2
        i2a = ldidx(k + 5, p0);  i2b = ldidx(k + 5, p1);
        mstep(Af, b0a, b0b);
        __builtin_amdgcn_sched_barrier(0);
        loadA(k + 1, Af);
        __builtin_amdgcn_sched_barrier(0);
        gather(b0a, baddr(i0a)); gather(b0b, baddr(i0b));   // k+3
        i0a = ldidx(k + 6, p0);  i0b = ldidx(k + 6, p1);
        mstep(Af, b1a, b1b);
        __builtin_amdgcn_sched_barrier(0);
        loadA(k + 2, Af);
        __builtin_amdgcn_sched_barrier(0);
        gather(b1a, baddr(i1a)); gather(b1b, baddr(i1b));   // k+4
        i1a = ldidx(k + 7, p0);  i1b = ldidx(k + 7, p1);
        mstep(Af, b2a, b2b);
        __builtin_amdgcn_sched_barrier(0);
    }
    // tail: b0=60, b1=61, s2 holds idx for 62
    loadA(60, Af);
    __builtin_amdgcn_sched_barrier(0);
    gather(b2a, baddr(i2a)); gather(b2b, baddr(i2b));
    mstep(Af, b0a, b0b);
    __builtin_amdgcn_sched_barrier(0);
    loadA(61, Af);
    __builtin_amdgcn_sched_barrier(0);
    mstep(Af, b1a, b1b);
    __builtin_amdgcn_sched_barrier(0);
    loadA(62, Af);
    __builtin_amdgcn_sched_barrier(0);
    mstep(Af, b2a, b2b);

    __syncthreads();   // wcs visibility

    // ---- epilogue: out[p][c] = x[p][c] + elu(acc)^T @ Wc ----
    // fully unrolled; all acc indices compile-time
    bf16* pb = &pbuf[wave * 2048];
#pragma unroll
    for (int pt = 0; pt < 2; pt++) {
#pragma unroll
        for (int mt = 0; mt < 2; mt++) {
#pragma unroll
            for (int q = 0; q < 4; q++) {
                bf16x4 v;
#pragma unroll
                for (int jj = 0; jj < 4; jj++)
                    v[jj] = (bf16)elu_f(acc[mt][pt][q * 4 + jj]);
                int chunk = mt * 4 + q;
                *(bf16x4*)&pb[l31 * 64 + ((chunk ^ (l31 & 7)) * 8) + 4 * half] = v;
            }
        }
        // per-wave buffer: same-wave LDS RAW handled by waitcnt, no barrier
        bf16x8 pa[4];
#pragma unroll
        for (int ks = 0; ks < 4; ks++) {
            int ci = 2 * ks + half;
            pa[ks] = *(const bf16x8*)&pb[l31 * 64 + ((ci ^ (l31 & 7)) * 8)];
        }
#pragma unroll
        for (int ct = 0; ct < 4; ct++) {
            f32x16 o;
#pragma unroll
            for (int r = 0; r < 16; r++) o[r] = 0.f;
            int cc = ct * 32 + l31;
#pragma unroll
            for (int ks = 0; ks < 4; ks++) {
                int ci = 2 * ks + half;
                bf16x8 bw = *(const bf16x8*)&wcs[cc * 64 + ((ci ^ (cc & 7)) * 8)];
                o = __builtin_amdgcn_mfma_f32_32x32x16_bf16(pa[ks], bw, o, 0, 0, 0);
            }
            int prow_base = pbase + pt * 32 + 4 * half;
#pragma unroll
            for (int r = 0; r < 16; r++) {
                int prow = prow_base + (r & 3) + 8 * (r >> 2);
                if (prow < N_PTS) {
                    size_t off = (size_t)prow * CD + cc;
                    out[off] = x[off] + o[r];
                }
            }
        }
    }
}

// ---------------------------------------------------------------------------
extern "C" void kernel_launch(void* const* d_in, const int* in_sizes, int n_in,
                              void* d_out, int out_size, void* d_ws, size_t ws_size,
                              hipStream_t stream) {
    const float* x  = (const float*)d_in[0];
    const float* y  = (const float*)d_in[1];
    const float* Wa = (const float*)d_in[2];
    const float* Wb = (const float*)d_in[3];
    const float* Wc = (const float*)d_in[4];
    const int* nidx = (const int*)d_in[5];
    float* out = (float*)d_out;

    char* ws = (char*)d_ws;
    bf16* f   = (bf16*)ws;                           // 200192*64*2 = 25,624,576 B
    bf16* WbT = (bf16*)(ws + 25624576);              // 63*4096*2   =    516,096 B
    bf16* WcT = (bf16*)(ws + 25624576 + 516096);     // 8192*2      =     16,384 B
    bf16* WaT = (bf16*)(ws + 25624576 + 516096 + 16384);   // 8192*2 = 16,384 B
    bf16* zp  = (bf16*)(ws + 25624576 + 516096 + 16384 + 16384);  // 128 B zeros

    k_prep<<<1073, 256, 0, stream>>>(Wb, Wc, Wa, WbT, WcT, WaT, zp);
    k_stage1<<<1564, 256, 0, stream>>>(x, y, WaT, f);
    k_conv<<<782, 256, 0, stream>>>(f, nidx, WbT, WcT, zp, x, out);
}